// Round 2
// baseline (2919.162 us; speedup 1.0000x reference)
//
#include <hip/hip_runtime.h>

#define N_NODES 100000
#define N_EDGES 3200000
#define F_IN 16
#define HID 32

// ---------------------------------------------------------------------------
// Kernel 1: weighted out-degree  deg[src[e]] += w[e]
// NOTE: harness delivers integer inputs as int32 (even though reference is
// int64) — cast d_in[1] to const int*. Round-1 crash was int64 misread.
// ---------------------------------------------------------------------------
__global__ __launch_bounds__(256) void deg_kernel(
    const int* __restrict__ src,
    const float* __restrict__ w,
    float* __restrict__ deg)
{
    int e = blockIdx.x * blockDim.x + threadIdx.x;
    if (e < N_EDGES) {
        unsafeAtomicAdd(&deg[src[e]], w[e]);
    }
}

// ---------------------------------------------------------------------------
// Kernel 2: deg -> dis = deg>0 ? rsqrt(max(deg,1e-12)) : 0   (in place)
// ---------------------------------------------------------------------------
__global__ __launch_bounds__(256) void dis_kernel(float* __restrict__ deg_dis)
{
    int i = blockIdx.x * blockDim.x + threadIdx.x;
    if (i < N_NODES) {
        float d = deg_dis[i];
        deg_dis[i] = (d > 0.f) ? rsqrtf(fmaxf(d, 1e-12f)) : 0.f;
    }
}

// ---------------------------------------------------------------------------
// Kernel 3: tx1[dst] += (-dis[src]*w*dis[dst]) * x[src]   (16-wide scatter)
// ---------------------------------------------------------------------------
__global__ __launch_bounds__(256) void scatter_kernel(
    const int* __restrict__ src,
    const int* __restrict__ dst,
    const float* __restrict__ w,
    const float* __restrict__ dis,
    const float* __restrict__ x,
    float* __restrict__ tx1)
{
    int e = blockIdx.x * blockDim.x + threadIdx.x;
    if (e >= N_EDGES) return;
    int s = src[e];
    int d = dst[e];
    float lw = -dis[s] * w[e] * dis[d];
    const float4* xr = (const float4*)(x + (size_t)s * F_IN);
    float4 a = xr[0], b = xr[1], c = xr[2], q = xr[3];
    float* t = tx1 + (size_t)d * F_IN;
    unsafeAtomicAdd(t + 0,  lw * a.x);
    unsafeAtomicAdd(t + 1,  lw * a.y);
    unsafeAtomicAdd(t + 2,  lw * a.z);
    unsafeAtomicAdd(t + 3,  lw * a.w);
    unsafeAtomicAdd(t + 4,  lw * b.x);
    unsafeAtomicAdd(t + 5,  lw * b.y);
    unsafeAtomicAdd(t + 6,  lw * b.z);
    unsafeAtomicAdd(t + 7,  lw * b.w);
    unsafeAtomicAdd(t + 8,  lw * c.x);
    unsafeAtomicAdd(t + 9,  lw * c.y);
    unsafeAtomicAdd(t + 10, lw * c.z);
    unsafeAtomicAdd(t + 11, lw * c.w);
    unsafeAtomicAdd(t + 12, lw * q.x);
    unsafeAtomicAdd(t + 13, lw * q.y);
    unsafeAtomicAdd(t + 14, lw * q.z);
    unsafeAtomicAdd(t + 15, lw * q.w);
}

// ---------------------------------------------------------------------------
// Kernel 4: per-node gate math + readout.
//   zpre = [x,tx1] @ [Wxz0;Wxz1] + (b_xz+b_hz)
//   hpre = [x,tx1] @ [Wxh0;Wxh1] + (b_xh+b_hh)
//   out  = relu((1-sigmoid(zpre))*tanh(hpre)) @ W_lin + b_lin
// (H == 0 in the reference; R is dead code since it only multiplies H.)
// ---------------------------------------------------------------------------
__global__ __launch_bounds__(256) void node_kernel(
    const float* __restrict__ x,
    const float* __restrict__ tx1,
    const float* __restrict__ W_xz, const float* __restrict__ b_xz,
    const float* __restrict__ b_hz,
    const float* __restrict__ W_xh, const float* __restrict__ b_xh,
    const float* __restrict__ b_hh,
    const float* __restrict__ W_lin, const float* __restrict__ b_lin,
    float* __restrict__ out)
{
    __shared__ float sWz[2 * F_IN * HID];   // [k0][k][j]
    __shared__ float sWh[2 * F_IN * HID];
    __shared__ float sbz[HID], sbh[HID], sWl[HID];

    for (int t = threadIdx.x; t < 2 * F_IN * HID; t += 256) {
        sWz[t] = W_xz[t];
        sWh[t] = W_xh[t];
    }
    if (threadIdx.x < HID) {
        sbz[threadIdx.x] = b_xz[threadIdx.x] + b_hz[threadIdx.x];
        sbh[threadIdx.x] = b_xh[threadIdx.x] + b_hh[threadIdx.x];
        sWl[threadIdx.x] = W_lin[threadIdx.x];
    }
    __syncthreads();

    int i = blockIdx.x * blockDim.x + threadIdx.x;
    if (i >= N_NODES) return;

    float xv[F_IN], tv[F_IN];
    const float4* xr = (const float4*)(x + (size_t)i * F_IN);
    const float4* tr = (const float4*)(tx1 + (size_t)i * F_IN);
#pragma unroll
    for (int q = 0; q < 4; ++q) {
        float4 a = xr[q];
        xv[4 * q + 0] = a.x; xv[4 * q + 1] = a.y; xv[4 * q + 2] = a.z; xv[4 * q + 3] = a.w;
        float4 b = tr[q];
        tv[4 * q + 0] = b.x; tv[4 * q + 1] = b.y; tv[4 * q + 2] = b.z; tv[4 * q + 3] = b.w;
    }

    float acc = 0.f;
    for (int j = 0; j < HID; ++j) {
        float zp = sbz[j];
        float hp = sbh[j];
#pragma unroll
        for (int k = 0; k < F_IN; ++k) {
            zp = fmaf(xv[k], sWz[k * HID + j], zp);
            zp = fmaf(tv[k], sWz[F_IN * HID + k * HID + j], zp);
            hp = fmaf(xv[k], sWh[k * HID + j], hp);
            hp = fmaf(tv[k], sWh[F_IN * HID + k * HID + j], hp);
        }
        float z  = 1.f / (1.f + __expf(-zp));
        float ht = tanhf(hp);
        float hn = (1.f - z) * ht;
        acc = fmaf(fmaxf(hn, 0.f), sWl[j], acc);
    }
    out[i] = acc + b_lin[0];
}

// ---------------------------------------------------------------------------
extern "C" void kernel_launch(void* const* d_in, const int* in_sizes, int n_in,
                              void* d_out, int out_size, void* d_ws, size_t ws_size,
                              hipStream_t stream)
{
    const float* x     = (const float*)d_in[0];
    const int*   ei    = (const int*)d_in[1];   // [2, E] delivered as int32
    const float* ew    = (const float*)d_in[2];
    const float* W_xz  = (const float*)d_in[3];
    const float* b_xz  = (const float*)d_in[4];
    const float* b_hz  = (const float*)d_in[6];
    const float* W_xh  = (const float*)d_in[11];
    const float* b_xh  = (const float*)d_in[12];
    const float* b_hh  = (const float*)d_in[14];
    const float* W_lin = (const float*)d_in[15];
    const float* b_lin = (const float*)d_in[16];
    float*       out   = (float*)d_out;

    // workspace layout: [dis: N floats][tx1: N*16 floats]
    float* dis = (float*)d_ws;
    float* tx1 = dis + N_NODES;

    hipMemsetAsync(d_ws, 0, (size_t)N_NODES * (1 + F_IN) * sizeof(float), stream);

    deg_kernel<<<(N_EDGES + 255) / 256, 256, 0, stream>>>(ei, ew, dis);
    dis_kernel<<<(N_NODES + 255) / 256, 256, 0, stream>>>(dis);
    scatter_kernel<<<(N_EDGES + 255) / 256, 256, 0, stream>>>(
        ei, ei + N_EDGES, ew, dis, x, tx1);
    node_kernel<<<(N_NODES + 255) / 256, 256, 0, stream>>>(
        x, tx1, W_xz, b_xz, b_hz, W_xh, b_xh, b_hh, W_lin, b_lin, out);
}

// Round 3
// 773.929 us; speedup vs baseline: 3.7719x; 3.7719x over previous
//
#include <hip/hip_runtime.h>

#define N_NODES 100000
#define N_EDGES 3200000
#define F_IN 16
#define HID 32
#define NB_SCAN ((N_NODES + 1023) / 1024)   // 98 scan blocks

// ---- workspace layout (units: 4-byte words, all 16B-aligned) ----
#define OFF_DEG      0          // N floats (deg, then dis in-place)
#define OFF_COUNTS   100000     // N ints
#define OFF_ROWPTR   200000     // N+1 ints (+pad)
#define OFF_CURSOR   300008     // N ints
#define OFF_BSUMS    400008     // 128 ints
#define OFF_BOFS     400136     // 128 ints
#define OFF_TX1      400264     // N*16 floats
#define OFF_SSRC     2000264    // E ints
#define OFF_SLW      5200264    // E floats
// total 8,400,264 words = 33.6 MB

// ---------------------------------------------------------------------------
// K1: counts[dst]++ (int) and deg[src] += w (fp32) in one edge pass
// ---------------------------------------------------------------------------
__global__ __launch_bounds__(256) void hist_deg_kernel(
    const int* __restrict__ src, const int* __restrict__ dst,
    const float* __restrict__ w,
    float* __restrict__ deg, int* __restrict__ counts)
{
    int e = blockIdx.x * 256 + threadIdx.x;
    if (e < N_EDGES) {
        atomicAdd(&counts[dst[e]], 1);
        unsafeAtomicAdd(&deg[src[e]], w[e]);
    }
}

// ---------------------------------------------------------------------------
// K2: deg -> dis in place
// ---------------------------------------------------------------------------
__global__ __launch_bounds__(256) void dis_kernel(float* __restrict__ deg_dis)
{
    int i = blockIdx.x * 256 + threadIdx.x;
    if (i < N_NODES) {
        float d = deg_dis[i];
        deg_dis[i] = (d > 0.f) ? rsqrtf(fmaxf(d, 1e-12f)) : 0.f;
    }
}

// ---------------------------------------------------------------------------
// K3a/b/c: hierarchical exclusive scan of counts -> row_ptr (+ cursor copy)
// ---------------------------------------------------------------------------
__global__ __launch_bounds__(1024) void scan1_kernel(
    const int* __restrict__ counts, int* __restrict__ row_ptr,
    int* __restrict__ bsums)
{
    __shared__ int s[1024];
    int t = threadIdx.x;
    int i = blockIdx.x * 1024 + t;
    int mine = (i < N_NODES) ? counts[i] : 0;
    s[t] = mine;
    __syncthreads();
    for (int off = 1; off < 1024; off <<= 1) {
        int u = (t >= off) ? s[t - off] : 0;
        __syncthreads();
        s[t] += u;
        __syncthreads();
    }
    if (i < N_NODES) row_ptr[i] = s[t] - mine;   // exclusive
    if (t == 1023) bsums[blockIdx.x] = s[1023];
}

__global__ void scan2_kernel(const int* __restrict__ bsums, int* __restrict__ bofs)
{
    if (threadIdx.x == 0 && blockIdx.x == 0) {
        int run = 0;
        for (int i = 0; i < NB_SCAN; ++i) { bofs[i] = run; run += bsums[i]; }
    }
}

__global__ __launch_bounds__(256) void scan3_kernel(
    int* __restrict__ row_ptr, int* __restrict__ cursor,
    const int* __restrict__ bofs)
{
    int i = blockIdx.x * 256 + threadIdx.x;
    if (i < N_NODES) {
        int v = row_ptr[i] + bofs[i >> 10];
        row_ptr[i] = v;
        cursor[i] = v;
        if (i == 0) row_ptr[N_NODES] = N_EDGES;
    }
}

// ---------------------------------------------------------------------------
// K4: bucket placement — sorted_src/sorted_lw grouped by dst
// ---------------------------------------------------------------------------
__global__ __launch_bounds__(256) void place_kernel(
    const int* __restrict__ src, const int* __restrict__ dst,
    const float* __restrict__ w, const float* __restrict__ dis,
    int* __restrict__ cursor, int* __restrict__ ssrc, float* __restrict__ slw)
{
    int e = blockIdx.x * 256 + threadIdx.x;
    if (e >= N_EDGES) return;
    int s = src[e], d = dst[e];
    float lw = -dis[s] * w[e] * dis[d];
    int pos = atomicAdd(&cursor[d], 1);
    ssrc[pos] = s;
    slw[pos] = lw;
}

// ---------------------------------------------------------------------------
// K5: gather — 4 threads per node (one per float4 quad), no atomics
// ---------------------------------------------------------------------------
__global__ __launch_bounds__(256) void gather_kernel(
    const int* __restrict__ row_ptr, const int* __restrict__ ssrc,
    const float* __restrict__ slw, const float* __restrict__ x,
    float* __restrict__ tx1)
{
    int gid = blockIdx.x * 256 + threadIdx.x;
    int n = gid >> 2;
    int q = gid & 3;
    if (n >= N_NODES) return;
    int j0 = row_ptr[n], j1 = row_ptr[n + 1];
    float4 acc = make_float4(0.f, 0.f, 0.f, 0.f);
    for (int j = j0; j < j1; ++j) {
        int s = ssrc[j];
        float lw = slw[j];
        float4 xv = *(const float4*)(x + (size_t)s * F_IN + q * 4);
        acc.x = fmaf(lw, xv.x, acc.x);
        acc.y = fmaf(lw, xv.y, acc.y);
        acc.z = fmaf(lw, xv.z, acc.z);
        acc.w = fmaf(lw, xv.w, acc.w);
    }
    *(float4*)(tx1 + (size_t)n * F_IN + q * 4) = acc;
}

// ---------------------------------------------------------------------------
// K6: per-node gate math + readout (H==0 => R dead, H-convs = biases)
// ---------------------------------------------------------------------------
__global__ __launch_bounds__(256) void node_kernel(
    const float* __restrict__ x,
    const float* __restrict__ tx1,
    const float* __restrict__ W_xz, const float* __restrict__ b_xz,
    const float* __restrict__ b_hz,
    const float* __restrict__ W_xh, const float* __restrict__ b_xh,
    const float* __restrict__ b_hh,
    const float* __restrict__ W_lin, const float* __restrict__ b_lin,
    float* __restrict__ out)
{
    __shared__ float sWz[2 * F_IN * HID];
    __shared__ float sWh[2 * F_IN * HID];
    __shared__ float sbz[HID], sbh[HID], sWl[HID];

    for (int t = threadIdx.x; t < 2 * F_IN * HID; t += 256) {
        sWz[t] = W_xz[t];
        sWh[t] = W_xh[t];
    }
    if (threadIdx.x < HID) {
        sbz[threadIdx.x] = b_xz[threadIdx.x] + b_hz[threadIdx.x];
        sbh[threadIdx.x] = b_xh[threadIdx.x] + b_hh[threadIdx.x];
        sWl[threadIdx.x] = W_lin[threadIdx.x];
    }
    __syncthreads();

    int i = blockIdx.x * 256 + threadIdx.x;
    if (i >= N_NODES) return;

    float xv[F_IN], tv[F_IN];
    const float4* xr = (const float4*)(x + (size_t)i * F_IN);
    const float4* tr = (const float4*)(tx1 + (size_t)i * F_IN);
#pragma unroll
    for (int q = 0; q < 4; ++q) {
        float4 a = xr[q];
        xv[4 * q + 0] = a.x; xv[4 * q + 1] = a.y; xv[4 * q + 2] = a.z; xv[4 * q + 3] = a.w;
        float4 b = tr[q];
        tv[4 * q + 0] = b.x; tv[4 * q + 1] = b.y; tv[4 * q + 2] = b.z; tv[4 * q + 3] = b.w;
    }

    float acc = 0.f;
    for (int j = 0; j < HID; ++j) {
        float zp = sbz[j];
        float hp = sbh[j];
#pragma unroll
        for (int k = 0; k < F_IN; ++k) {
            zp = fmaf(xv[k], sWz[k * HID + j], zp);
            zp = fmaf(tv[k], sWz[F_IN * HID + k * HID + j], zp);
            hp = fmaf(xv[k], sWh[k * HID + j], hp);
            hp = fmaf(tv[k], sWh[F_IN * HID + k * HID + j], hp);
        }
        float z  = 1.f / (1.f + __expf(-zp));
        float ht = tanhf(hp);
        float hn = (1.f - z) * ht;
        acc = fmaf(fmaxf(hn, 0.f), sWl[j], acc);
    }
    out[i] = acc + b_lin[0];
}

// ---------------------------------------------------------------------------
extern "C" void kernel_launch(void* const* d_in, const int* in_sizes, int n_in,
                              void* d_out, int out_size, void* d_ws, size_t ws_size,
                              hipStream_t stream)
{
    const float* x     = (const float*)d_in[0];
    const int*   ei    = (const int*)d_in[1];   // [2, E] delivered as int32
    const float* ew    = (const float*)d_in[2];
    const float* W_xz  = (const float*)d_in[3];
    const float* b_xz  = (const float*)d_in[4];
    const float* b_hz  = (const float*)d_in[6];
    const float* W_xh  = (const float*)d_in[11];
    const float* b_xh  = (const float*)d_in[12];
    const float* b_hh  = (const float*)d_in[14];
    const float* W_lin = (const float*)d_in[15];
    const float* b_lin = (const float*)d_in[16];
    float*       out   = (float*)d_out;

    float* wsf = (float*)d_ws;
    int*   wsi = (int*)d_ws;

    float* deg     = wsf + OFF_DEG;     // becomes dis in place
    int*   counts  = wsi + OFF_COUNTS;
    int*   row_ptr = wsi + OFF_ROWPTR;
    int*   cursor  = wsi + OFF_CURSOR;
    int*   bsums   = wsi + OFF_BSUMS;
    int*   bofs    = wsi + OFF_BOFS;
    float* tx1     = wsf + OFF_TX1;
    int*   ssrc    = wsi + OFF_SSRC;
    float* slw     = wsf + OFF_SLW;

    const int* src = ei;
    const int* dst = ei + N_EDGES;

    // zero deg + counts only (everything else fully overwritten each call)
    hipMemsetAsync(d_ws, 0, (size_t)2 * N_NODES * sizeof(float), stream);

    hist_deg_kernel<<<(N_EDGES + 255) / 256, 256, 0, stream>>>(src, dst, ew, deg, counts);
    dis_kernel<<<(N_NODES + 255) / 256, 256, 0, stream>>>(deg);
    scan1_kernel<<<NB_SCAN, 1024, 0, stream>>>(counts, row_ptr, bsums);
    scan2_kernel<<<1, 64, 0, stream>>>(bsums, bofs);
    scan3_kernel<<<(N_NODES + 255) / 256, 256, 0, stream>>>(row_ptr, cursor, bofs);
    place_kernel<<<(N_EDGES + 255) / 256, 256, 0, stream>>>(src, dst, ew, deg, cursor, ssrc, slw);
    gather_kernel<<<(4 * N_NODES + 255) / 256, 256, 0, stream>>>(row_ptr, ssrc, slw, x, tx1);
    node_kernel<<<(N_NODES + 255) / 256, 256, 0, stream>>>(
        x, tx1, W_xz, b_xz, b_hz, W_xh, b_xh, b_hh, W_lin, b_lin, out);
}

// Round 4
// 604.146 us; speedup vs baseline: 4.8319x; 1.2810x over previous
//
#include <hip/hip_runtime.h>

#define N_NODES 100000
#define N_EDGES 3200000
#define F_IN 16
#define HID 32

#define NPB 256                         // nodes per coarse bin
#define NBIN 391                        // ceil(N_NODES / NPB)
#define NBLK_A 512                      // blocks in edge passes
#define EPB (N_EDGES / NBLK_A)          // 6250 edges per block (exact)
#define NHIST (2 * NBIN * NBLK_A)       // 400384 = 391 * 1024 (exact)
#define NB_S1 (NHIST / 1024)            // 391 scan blocks (exact)

// ---- workspace layout (4-byte words) ----
#define OFF_HIST 0                      // NHIST ints (hist, scanned in place)
#define OFF_BSUM 400384                 // 391 ints
#define OFF_BOFS 400776                 // 391 ints
#define OFF_DIS  401168                 // N_NODES floats
#define OFF_EB   501168                 // 2*E uint2 = 12.8M words (8B aligned)
// total 13,301,168 words = 53.2 MB

// ---------------------------------------------------------------------------
// A1: per-block LDS histograms of dst-bins and src-bins (no global atomics).
// hist layout: hist[bin * NBLK_A + blk]; dst bins 0..390, src bins 391..781.
// ---------------------------------------------------------------------------
__global__ __launch_bounds__(256) void histA(
    const int* __restrict__ src, const int* __restrict__ dst,
    int* __restrict__ hist)
{
    __shared__ int hd[NBIN], hs[NBIN];
    for (int i = threadIdx.x; i < NBIN; i += 256) { hd[i] = 0; hs[i] = 0; }
    __syncthreads();
    int base = blockIdx.x * EPB;
    for (int k = threadIdx.x; k < EPB; k += 256) {
        int e = base + k;
        atomicAdd(&hd[dst[e] >> 8], 1);
        atomicAdd(&hs[src[e] >> 8], 1);
    }
    __syncthreads();
    for (int i = threadIdx.x; i < NBIN; i += 256) {
        hist[i * NBLK_A + blockIdx.x] = hd[i];
        hist[(NBIN + i) * NBLK_A + blockIdx.x] = hs[i];
    }
}

// ---------------------------------------------------------------------------
// Joint exclusive scan over the 400384-entry count matrix (in place).
// ---------------------------------------------------------------------------
__global__ __launch_bounds__(1024) void scan1(int* __restrict__ a, int* __restrict__ bsums)
{
    __shared__ int s[1024];
    int t = threadIdx.x;
    int i = blockIdx.x * 1024 + t;           // NHIST == NB_S1*1024 exactly
    int mine = a[i];
    s[t] = mine;
    __syncthreads();
    for (int off = 1; off < 1024; off <<= 1) {
        int u = (t >= off) ? s[t - off] : 0;
        __syncthreads();
        s[t] += u;
        __syncthreads();
    }
    a[i] = s[t] - mine;                      // exclusive within block
    if (t == 1023) bsums[blockIdx.x] = s[1023];
}

__global__ __launch_bounds__(512) void scan2(const int* __restrict__ bsums, int* __restrict__ bofs)
{
    __shared__ int s[512];
    int t = threadIdx.x;
    int mine = (t < NB_S1) ? bsums[t] : 0;
    s[t] = mine;
    __syncthreads();
    for (int off = 1; off < 512; off <<= 1) {
        int u = (t >= off) ? s[t - off] : 0;
        __syncthreads();
        s[t] += u;
        __syncthreads();
    }
    if (t < NB_S1) bofs[t] = s[t] - mine;
}

__global__ __launch_bounds__(256) void scan3(int* __restrict__ a, const int* __restrict__ bofs)
{
    int i = blockIdx.x * 256 + threadIdx.x;  // NHIST/256 = 1564 exactly
    a[i] += bofs[i >> 10];
}

// ---------------------------------------------------------------------------
// A2: scatter edges into the two bucketed structures (LDS cursors only).
//   dst-structure (eb[0,E)):  .x = src | dstlow<<17   .y = bits(w)
//   src-structure (eb[E,2E)): .x = srclow             .y = bits(w)
// ---------------------------------------------------------------------------
__global__ __launch_bounds__(256) void scatterA(
    const int* __restrict__ src, const int* __restrict__ dst,
    const float* __restrict__ w, const int* __restrict__ scanned,
    uint2* __restrict__ eb)
{
    __shared__ int cur[2 * NBIN];
    for (int i = threadIdx.x; i < 2 * NBIN; i += 256)
        cur[i] = scanned[i * NBLK_A + blockIdx.x];
    __syncthreads();
    int base = blockIdx.x * EPB;
    for (int k = threadIdx.x; k < EPB; k += 256) {
        int e = base + k;
        int s = src[e], d = dst[e];
        unsigned wb = __float_as_uint(w[e]);
        int pd = atomicAdd(&cur[d >> 8], 1);
        eb[pd] = make_uint2((unsigned)s | ((unsigned)(d & 255) << 17), wb);
        int ps = atomicAdd(&cur[NBIN + (s >> 8)], 1);
        eb[ps] = make_uint2((unsigned)(s & 255), wb);
    }
}

// ---------------------------------------------------------------------------
// B_src: per-bucket deg reduction in LDS -> dis (no global atomics).
// ---------------------------------------------------------------------------
__global__ __launch_bounds__(256) void degK(
    const uint2* __restrict__ eb, const int* __restrict__ scanned,
    float* __restrict__ dis)
{
    __shared__ float sdeg[NPB];
    int b = blockIdx.x;
    sdeg[threadIdx.x] = 0.f;
    __syncthreads();
    int j0 = scanned[(NBIN + b) * NBLK_A];
    int j1 = (b == NBIN - 1) ? 2 * N_EDGES : scanned[(NBIN + b + 1) * NBLK_A];
    for (int j = j0 + threadIdx.x; j < j1; j += 256) {
        uint2 v = eb[j];
        atomicAdd(&sdeg[v.x & 255], __uint_as_float(v.y));
    }
    __syncthreads();
    int n = b * NPB + threadIdx.x;
    if (n < N_NODES) {
        float dg = sdeg[threadIdx.x];
        dis[n] = (dg > 0.f) ? rsqrtf(fmaxf(dg, 1e-12f)) : 0.f;
    }
}

// ---------------------------------------------------------------------------
// B_dst + node epilogue fused: accumulate tx1 for 256 nodes in LDS
// (stride 17 to break bank aliasing), then gate math + readout.
//   zpre = [x,tx1]@[Wxz0;Wxz1] + (b_xz+b_hz); hpre likewise with Wxh
//   out  = relu((1-sigmoid(zpre))*tanh(hpre)) @ W_lin + b_lin
// (H == 0 in the reference; R is dead since it only multiplies H.)
// ---------------------------------------------------------------------------
__global__ __launch_bounds__(256) void gatherNode(
    const uint2* __restrict__ eb, const int* __restrict__ scanned,
    const float* __restrict__ dis, const float* __restrict__ x,
    const float* __restrict__ W_xz, const float* __restrict__ b_xz,
    const float* __restrict__ b_hz,
    const float* __restrict__ W_xh, const float* __restrict__ b_xh,
    const float* __restrict__ b_hh,
    const float* __restrict__ W_lin, const float* __restrict__ b_lin,
    float* __restrict__ out)
{
    __shared__ float stx[NPB * 17];
    __shared__ float sWz[2 * F_IN * HID], sWh[2 * F_IN * HID];
    __shared__ float sbz[HID], sbh[HID], sWl[HID];
    __shared__ float sdis[NPB];

    int t = threadIdx.x, b = blockIdx.x;
    for (int i = t; i < NPB * 17; i += 256) stx[i] = 0.f;
    for (int i = t; i < 2 * F_IN * HID; i += 256) { sWz[i] = W_xz[i]; sWh[i] = W_xh[i]; }
    if (t < HID) {
        sbz[t] = b_xz[t] + b_hz[t];
        sbh[t] = b_xh[t] + b_hh[t];
        sWl[t] = W_lin[t];
    }
    {
        int n = b * NPB + t;
        sdis[t] = (n < N_NODES) ? dis[n] : 0.f;
    }
    __syncthreads();

    int j0 = scanned[b * NBLK_A];
    int j1 = (b == NBIN - 1) ? N_EDGES : scanned[(b + 1) * NBLK_A];
    for (int j = j0 + t; j < j1; j += 256) {
        uint2 v = eb[j];
        int s  = v.x & 0x1FFFF;
        int dl = v.x >> 17;
        float lw = -dis[s] * __uint_as_float(v.y) * sdis[dl];
        const float4* xr = (const float4*)(x + (size_t)s * F_IN);
        float* tp = &stx[dl * 17];
        float4 a = xr[0];
        atomicAdd(tp + 0,  lw * a.x); atomicAdd(tp + 1,  lw * a.y);
        atomicAdd(tp + 2,  lw * a.z); atomicAdd(tp + 3,  lw * a.w);
        float4 c = xr[1];
        atomicAdd(tp + 4,  lw * c.x); atomicAdd(tp + 5,  lw * c.y);
        atomicAdd(tp + 6,  lw * c.z); atomicAdd(tp + 7,  lw * c.w);
        float4 g = xr[2];
        atomicAdd(tp + 8,  lw * g.x); atomicAdd(tp + 9,  lw * g.y);
        atomicAdd(tp + 10, lw * g.z); atomicAdd(tp + 11, lw * g.w);
        float4 h = xr[3];
        atomicAdd(tp + 12, lw * h.x); atomicAdd(tp + 13, lw * h.y);
        atomicAdd(tp + 14, lw * h.z); atomicAdd(tp + 15, lw * h.w);
    }
    __syncthreads();

    int n = b * NPB + t;
    if (n >= N_NODES) return;

    float xv[F_IN], tv[F_IN];
    const float4* xr = (const float4*)(x + (size_t)n * F_IN);
#pragma unroll
    for (int q = 0; q < 4; ++q) {
        float4 a = xr[q];
        xv[4 * q + 0] = a.x; xv[4 * q + 1] = a.y; xv[4 * q + 2] = a.z; xv[4 * q + 3] = a.w;
    }
#pragma unroll
    for (int k = 0; k < F_IN; ++k) tv[k] = stx[t * 17 + k];

    float acc = 0.f;
    for (int j = 0; j < HID; ++j) {
        float zp = sbz[j];
        float hp = sbh[j];
#pragma unroll
        for (int k = 0; k < F_IN; ++k) {
            zp = fmaf(xv[k], sWz[k * HID + j], zp);
            zp = fmaf(tv[k], sWz[F_IN * HID + k * HID + j], zp);
            hp = fmaf(xv[k], sWh[k * HID + j], hp);
            hp = fmaf(tv[k], sWh[F_IN * HID + k * HID + j], hp);
        }
        float z  = 1.f / (1.f + __expf(-zp));
        float ht = tanhf(hp);
        float hn = (1.f - z) * ht;
        acc = fmaf(fmaxf(hn, 0.f), sWl[j], acc);
    }
    out[n] = acc + b_lin[0];
}

// ---------------------------------------------------------------------------
extern "C" void kernel_launch(void* const* d_in, const int* in_sizes, int n_in,
                              void* d_out, int out_size, void* d_ws, size_t ws_size,
                              hipStream_t stream)
{
    const float* x     = (const float*)d_in[0];
    const int*   ei    = (const int*)d_in[1];   // [2, E] delivered as int32
    const float* ew    = (const float*)d_in[2];
    const float* W_xz  = (const float*)d_in[3];
    const float* b_xz  = (const float*)d_in[4];
    const float* b_hz  = (const float*)d_in[6];
    const float* W_xh  = (const float*)d_in[11];
    const float* b_xh  = (const float*)d_in[12];
    const float* b_hh  = (const float*)d_in[14];
    const float* W_lin = (const float*)d_in[15];
    const float* b_lin = (const float*)d_in[16];
    float*       out   = (float*)d_out;

    int*   wsi = (int*)d_ws;
    float* wsf = (float*)d_ws;

    int*   hist  = wsi + OFF_HIST;   // scanned in place
    int*   bsums = wsi + OFF_BSUM;
    int*   bofs  = wsi + OFF_BOFS;
    float* dis   = wsf + OFF_DIS;
    uint2* eb    = (uint2*)(wsi + OFF_EB);

    const int* src = ei;
    const int* dst = ei + N_EDGES;

    histA<<<NBLK_A, 256, 0, stream>>>(src, dst, hist);
    scan1<<<NB_S1, 1024, 0, stream>>>(hist, bsums);
    scan2<<<1, 512, 0, stream>>>(bsums, bofs);
    scan3<<<NHIST / 256, 256, 0, stream>>>(hist, bofs);
    scatterA<<<NBLK_A, 256, 0, stream>>>(src, dst, ew, hist, eb);
    degK<<<NBIN, 256, 0, stream>>>(eb, hist, dis);
    gatherNode<<<NBIN, 256, 0, stream>>>(eb, hist, dis, x,
        W_xz, b_xz, b_hz, W_xh, b_xh, b_hh, W_lin, b_lin, out);
}